// Round 2
// baseline (673.682 us; speedup 1.0000x reference)
//
#include <hip/hip_runtime.h>
#include <hip/hip_bf16.h>

#define MQ 65536
#define NKEY 65536
#define KNB 16
#define CCH 64

typedef _Float16 half8 __attribute__((ext_vector_type(8)));
typedef float floatx4 __attribute__((ext_vector_type(4)));

// ---------------- mask dtype detection ----------------
// Classifies mask storage by byte-position signature over the first 64 KiB:
//   bit0: nonzero byte at pos%4==0   (int32 0/1 -> only this)
//   bit1: nonzero byte at pos%4==1   (byte-bool -> bits 0,1,2 all set)
//   bit2: nonzero byte at pos%4 in {2,3} (float32 1.0f -> only this)
// Decode: bit1 ? byte-bool : (bit0 ? int32 : float32)
__global__ void detect_mask(const unsigned char* __restrict__ m, int* __restrict__ flag)
{
    __shared__ int sflags;
    if (threadIdx.x == 0) sflags = 0;
    __syncthreads();
    int local = 0;
    for (int i = threadIdx.x; i < 65536; i += 256) {
        unsigned char b = m[i];
        if (b) {
            int p = i & 3;
            local |= (p == 0) ? 1 : ((p == 1) ? 2 : 4);
        }
    }
    if (local) atomicOr(&sflags, local);
    __syncthreads();
    if (threadIdx.x == 0) *flag = sflags;
}

// ---------------- Kernel A: qp = (q+q_pos)@Wqk+b ; kp = (k+k_pos)@Wqk+b ----------------
__global__ __launch_bounds__(256, 2)
void proj_qk(const float* __restrict__ q, const float* __restrict__ qpos,
             const float* __restrict__ k, const float* __restrict__ kpos,
             const float* __restrict__ Wqk, const float* __restrict__ bqk,
             float* __restrict__ qp, float* __restrict__ kp)
{
    __shared__ __align__(16) _Float16 A_s[256 * 72];
    __shared__ __align__(16) _Float16 WT_s[64 * 72];

    const int tid = threadIdx.x;
    const int r0 = blockIdx.x * 256;
    const float* x; const float* p; float* o; int rb;
    if (r0 < MQ) { x = q; p = qpos; o = qp; rb = r0; }
    else         { x = k; p = kpos; o = kp; rb = r0 - MQ; }

    for (int i = tid; i < 64 * 64; i += 256) {
        int rr = i >> 6, c = i & 63;
        WT_s[c * 72 + rr] = (_Float16)Wqk[i];
    }
    for (int i = tid; i < 256 * 64; i += 256) {
        int rr = i >> 6, c = i & 63;
        size_t g = (size_t)(rb + rr) * 64 + c;
        A_s[rr * 72 + c] = (_Float16)(x[g] + p[g]);
    }
    __syncthreads();

    const int w = tid >> 6, lane = tid & 63, m = lane & 15, qd = lane >> 4;
    const floatx4 fz = {0.f, 0.f, 0.f, 0.f};
    floatx4 acc[4][4];
    #pragma unroll
    for (int rt = 0; rt < 4; rt++)
        #pragma unroll
        for (int ct = 0; ct < 4; ct++) acc[rt][ct] = fz;

    #pragma unroll
    for (int kc = 0; kc < 2; ++kc) {
        const int k0 = kc * 32 + qd * 8;
        half8 b[4];
        #pragma unroll
        for (int ct = 0; ct < 4; ++ct)
            b[ct] = *(const half8*)&WT_s[(ct * 16 + m) * 72 + k0];
        #pragma unroll
        for (int rt = 0; rt < 4; ++rt) {
            half8 a = *(const half8*)&A_s[(w * 64 + rt * 16 + m) * 72 + k0];
            #pragma unroll
            for (int ct = 0; ct < 4; ++ct)
                acc[rt][ct] = __builtin_amdgcn_mfma_f32_16x16x32_f16(a, b[ct], acc[rt][ct], 0, 0, 0);
        }
    }
    #pragma unroll
    for (int rt = 0; rt < 4; rt++) {
        #pragma unroll
        for (int ct = 0; ct < 4; ct++) {
            const int col = ct * 16 + m;
            const float bb = bqk[col];
            #pragma unroll
            for (int rg = 0; rg < 4; ++rg) {
                const int row = rb + w * 64 + rt * 16 + qd * 4 + rg;
                o[(size_t)row * 64 + col] = acc[rt][ct][rg] + bb;
            }
        }
    }
}

// ---------------- Kernel B: fused edge-MLP + softmax + aggregate + out proj ----------------
__global__ __launch_bounds__(256, 2)
void cross_attn(const float* __restrict__ value, const unsigned char* __restrict__ maskraw,
                const int* __restrict__ mflag,
                const int* __restrict__ idx,
                const float* __restrict__ qp, const float* __restrict__ kp,
                const float* __restrict__ Wg1, const float* __restrict__ bg1,
                const float* __restrict__ Wg2, const float* __restrict__ bg2,
                const float* __restrict__ Wv,  const float* __restrict__ bv,
                const float* __restrict__ Wt,  const float* __restrict__ bt,
                float* __restrict__ out)
{
    __shared__ __align__(16) _Float16 D_s[256 * 72];
    __shared__ __align__(16) _Float16 Wg1T[64 * 72];
    __shared__ __align__(16) _Float16 Wg2T[64 * 72];
    __shared__ __align__(16) _Float16 WvT [64 * 72];
    __shared__ __align__(16) _Float16 WtT [64 * 72];
    __shared__ __align__(16) _Float16 res_s[16 * 72];
    __shared__ unsigned char mask_s[256];

    const int tid = threadIdx.x;
    const int q0 = blockIdx.x * 16;

    for (int i = tid; i < 64 * 64; i += 256) {
        int rr = i >> 6, c = i & 63;
        Wg1T[c * 72 + rr] = (_Float16)Wg1[i];
        Wg2T[c * 72 + rr] = (_Float16)Wg2[i];
        WvT [c * 72 + rr] = (_Float16)Wv[i];
        WtT [c * 72 + rr] = (_Float16)Wt[i];
    }
    {
        // mask element for edge (q0*16 + tid), storage format per detected mode
        const int mode = *mflag;
        const size_t ei = (size_t)q0 * KNB + tid;
        unsigned char mv;
        if (mode & 2)      mv = maskraw[ei];                                  // byte-bool
        else if (mode & 1) mv = ((const int*)maskraw)[ei] ? 1 : 0;            // int32
        else               mv = (((const float*)maskraw)[ei] != 0.f) ? 1 : 0; // float32
        mask_s[tid] = mv;
    }
    {
        const int c = tid & 63;
        for (int e = tid >> 6; e < 256; e += 4) {
            const int ql = e >> 4, kn = e & 15;
            const int mrow = q0 + ql;
            const int nb = idx[mrow * KNB + kn];
            const float d = qp[(size_t)mrow * 64 + c] - kp[(size_t)nb * 64 + c];
            D_s[e * 72 + c] = (_Float16)d;
        }
    }
    __syncthreads();

    const int w = tid >> 6, lane = tid & 63, m = lane & 15, qd = lane >> 4;
    const floatx4 fz = {0.f, 0.f, 0.f, 0.f};

    float bvv[4], bg1v[4], bg2v[4];
    #pragma unroll
    for (int ct = 0; ct < 4; ct++) {
        const int col = ct * 16 + m;
        bvv[ct] = bv[col]; bg1v[ct] = bg1[col]; bg2v[ct] = bg2[col];
    }

    // ---- v = value @ Wv (A-frags straight from global) ----
    floatx4 accv[4][4];
    #pragma unroll
    for (int rt = 0; rt < 4; rt++)
        #pragma unroll
        for (int ct = 0; ct < 4; ct++) accv[rt][ct] = fz;
    #pragma unroll
    for (int kc = 0; kc < 2; ++kc) {
        const int k0 = kc * 32 + qd * 8;
        half8 b[4];
        #pragma unroll
        for (int ct = 0; ct < 4; ++ct)
            b[ct] = *(const half8*)&WvT[(ct * 16 + m) * 72 + k0];
        #pragma unroll
        for (int rt = 0; rt < 4; ++rt) {
            const size_t grow = (size_t)q0 * KNB + w * 64 + rt * 16 + m;
            const float* vr = value + grow * 64 + k0;
            floatx4 x0 = *(const floatx4*)vr;
            floatx4 x1 = *(const floatx4*)(vr + 4);
            half8 a;
            #pragma unroll
            for (int j = 0; j < 4; ++j) { a[j] = (_Float16)x0[j]; a[4 + j] = (_Float16)x1[j]; }
            #pragma unroll
            for (int ct = 0; ct < 4; ++ct)
                accv[rt][ct] = __builtin_amdgcn_mfma_f32_16x16x32_f16(a, b[ct], accv[rt][ct], 0, 0, 0);
        }
    }

    // ---- h = relu(d @ Wg1 + bg1) ----
    floatx4 acce[4][4];
    #pragma unroll
    for (int rt = 0; rt < 4; rt++)
        #pragma unroll
        for (int ct = 0; ct < 4; ct++) acce[rt][ct] = fz;
    #pragma unroll
    for (int kc = 0; kc < 2; ++kc) {
        const int k0 = kc * 32 + qd * 8;
        half8 b[4];
        #pragma unroll
        for (int ct = 0; ct < 4; ++ct)
            b[ct] = *(const half8*)&Wg1T[(ct * 16 + m) * 72 + k0];
        #pragma unroll
        for (int rt = 0; rt < 4; ++rt) {
            half8 a = *(const half8*)&D_s[(w * 64 + rt * 16 + m) * 72 + k0];
            #pragma unroll
            for (int ct = 0; ct < 4; ++ct)
                acce[rt][ct] = __builtin_amdgcn_mfma_f32_16x16x32_f16(a, b[ct], acce[rt][ct], 0, 0, 0);
        }
    }
    __syncthreads();
    #pragma unroll
    for (int rt = 0; rt < 4; rt++)
        #pragma unroll
        for (int ct = 0; ct < 4; ct++) {
            const int col = ct * 16 + m;
            #pragma unroll
            for (int rg = 0; rg < 4; ++rg) {
                const int row = w * 64 + rt * 16 + qd * 4 + rg;
                float h = acce[rt][ct][rg] + bg1v[ct];
                D_s[row * 72 + col] = (_Float16)fmaxf(h, 0.f);
            }
        }
    __syncthreads();

    // ---- e = h @ Wg2 + bg2 ----
    #pragma unroll
    for (int rt = 0; rt < 4; rt++)
        #pragma unroll
        for (int ct = 0; ct < 4; ct++) acce[rt][ct] = fz;
    #pragma unroll
    for (int kc = 0; kc < 2; ++kc) {
        const int k0 = kc * 32 + qd * 8;
        half8 b[4];
        #pragma unroll
        for (int ct = 0; ct < 4; ++ct)
            b[ct] = *(const half8*)&Wg2T[(ct * 16 + m) * 72 + k0];
        #pragma unroll
        for (int rt = 0; rt < 4; ++rt) {
            half8 a = *(const half8*)&D_s[(w * 64 + rt * 16 + m) * 72 + k0];
            #pragma unroll
            for (int ct = 0; ct < 4; ++ct)
                acce[rt][ct] = __builtin_amdgcn_mfma_f32_16x16x32_f16(a, b[ct], acce[rt][ct], 0, 0, 0);
        }
    }

    // ---- mask, softmax over kn, weighted aggregate ----
    #pragma unroll
    for (int rt = 0; rt < 4; rt++) {
        #pragma unroll
        for (int ct = 0; ct < 4; ct++) {
            float ev[4];
            #pragma unroll
            for (int rg = 0; rg < 4; ++rg) {
                const int erow = w * 64 + rt * 16 + qd * 4 + rg;
                float e = acce[rt][ct][rg] + bg2v[ct];
                ev[rg] = mask_s[erow] ? -1e12f : e;
            }
            float mx = fmaxf(fmaxf(ev[0], ev[1]), fmaxf(ev[2], ev[3]));
            mx = fmaxf(mx, __shfl_xor(mx, 16));
            mx = fmaxf(mx, __shfl_xor(mx, 32));
            float p[4], s = 0.f;
            #pragma unroll
            for (int rg = 0; rg < 4; ++rg) { p[rg] = __expf(ev[rg] - mx); s += p[rg]; }
            s += __shfl_xor(s, 16);
            s += __shfl_xor(s, 32);
            const float inv = 1.f / s;
            float t = 0.f;
            #pragma unroll
            for (int rg = 0; rg < 4; ++rg)
                t += p[rg] * inv * (accv[rt][ct][rg] + bvv[ct]);
            t += __shfl_xor(t, 16);
            t += __shfl_xor(t, 32);
            if (lane < 16) res_s[(w * 4 + rt) * 72 + ct * 16 + m] = (_Float16)t;
        }
    }
    __syncthreads();

    // ---- out = res @ Wt + bt (wave 0) ----
    if (w == 0) {
        floatx4 acco[4] = {fz, fz, fz, fz};
        #pragma unroll
        for (int kc = 0; kc < 2; ++kc) {
            const int k0 = kc * 32 + qd * 8;
            half8 a = *(const half8*)&res_s[m * 72 + k0];
            #pragma unroll
            for (int ct = 0; ct < 4; ++ct) {
                half8 b = *(const half8*)&WtT[(ct * 16 + m) * 72 + k0];
                acco[ct] = __builtin_amdgcn_mfma_f32_16x16x32_f16(a, b, acco[ct], 0, 0, 0);
            }
        }
        #pragma unroll
        for (int ct = 0; ct < 4; ++ct) {
            const int col = ct * 16 + m;
            const float bb = bt[col];
            #pragma unroll
            for (int rg = 0; rg < 4; ++rg) {
                const int row = qd * 4 + rg;
                out[(size_t)(q0 + row) * 64 + col] = acco[ct][rg] + bb;
            }
        }
    }
}

extern "C" void kernel_launch(void* const* d_in, const int* in_sizes, int n_in,
                              void* d_out, int out_size, void* d_ws, size_t ws_size,
                              hipStream_t stream) {
    const float* q     = (const float*)d_in[0];
    const float* k     = (const float*)d_in[1];
    const float* value = (const float*)d_in[2];
    const float* q_pos = (const float*)d_in[3];
    const float* k_pos = (const float*)d_in[4];
    const unsigned char* mask = (const unsigned char*)d_in[5];
    const int* knn     = (const int*)d_in[6];
    // d_in[7] = k_num scalar (16)
    const float* Wqk = (const float*)d_in[8];
    const float* bqk = (const float*)d_in[9];
    const float* Wv  = (const float*)d_in[10];
    const float* bv  = (const float*)d_in[11];
    const float* Wg1 = (const float*)d_in[12];
    const float* bg1 = (const float*)d_in[13];
    const float* Wg2 = (const float*)d_in[14];
    const float* bg2 = (const float*)d_in[15];
    const float* Wt  = (const float*)d_in[16];
    const float* bt  = (const float*)d_in[17];
    float* out = (float*)d_out;

    float* qp = (float*)d_ws;                    // [M][64] fp32
    float* kp = qp + (size_t)MQ * CCH;           // [N][64] fp32
    int* mflag = (int*)(kp + (size_t)NKEY * CCH);
    const int* idx = knn + (size_t)MQ * KNB;     // row 1 of knearest_idx

    detect_mask<<<1, 256, 0, stream>>>(mask, mflag);
    proj_qk<<<(MQ + NKEY) / 256, 256, 0, stream>>>(q, q_pos, k, k_pos, Wqk, bqk, qp, kp);
    cross_attn<<<MQ / 16, 256, 0, stream>>>(value, mask, mflag, idx, qp, kp,
                                            Wg1, bg1, Wg2, bg2, Wv, bv, Wt, bt, out);
}

// Round 3
// 537.961 us; speedup vs baseline: 1.2523x; 1.2523x over previous
//
#include <hip/hip_runtime.h>
#include <hip/hip_bf16.h>

#define MQ 65536
#define NKEY 65536
#define KNB 16
#define CCH 64

typedef _Float16 half8  __attribute__((ext_vector_type(8)));
typedef _Float16 half4v __attribute__((ext_vector_type(4)));
typedef _Float16 half2v __attribute__((ext_vector_type(2)));
typedef float    floatx4 __attribute__((ext_vector_type(4)));

// ws layout:
//   qp_h  : _Float16[MQ*64]      (8.39 MB)
//   kp_h  : _Float16[NKEY*64]    (8.39 MB)
//   w4    : _Float16[4*64*72]    (36,864 B)  f16, transposed (WT[out][in]), padded rows of 72
//   mflag : int

// ---------------- Kernel A: projections + (block 512) mask-detect + weight conversion ----------------
__global__ __launch_bounds__(256, 2)
void proj_prep(const float* __restrict__ q, const float* __restrict__ qpos,
               const float* __restrict__ k, const float* __restrict__ kpos,
               const float* __restrict__ Wqk, const float* __restrict__ bqk,
               const float* __restrict__ Wg1, const float* __restrict__ Wg2,
               const float* __restrict__ Wv,  const float* __restrict__ Wt,
               const unsigned char* __restrict__ maskraw,
               _Float16* __restrict__ qp_h, _Float16* __restrict__ kp_h,
               _Float16* __restrict__ w4, int* __restrict__ mflag)
{
    const int tid = threadIdx.x;

    if (blockIdx.x == 512) {
        // ---- mask dtype detect: byte-position signature over first 16 KiB ----
        __shared__ int sflags;
        if (tid == 0) sflags = 0;
        __syncthreads();
        const uint4* m4 = (const uint4*)maskraw;
        unsigned int orw = 0;
        #pragma unroll
        for (int it = 0; it < 4; ++it) {
            uint4 v = m4[tid + it * 256];
            orw |= v.x | v.y | v.z | v.w;
        }
        int local = 0;
        if (orw & 0x000000FFu) local |= 1;   // pos%4==0 nonzero
        if (orw & 0x0000FF00u) local |= 2;   // pos%4==1 nonzero (byte-bool)
        if (orw & 0xFFFF0000u) local |= 4;   // pos%4 in {2,3} (float32 1.0f)
        if (local) atomicOr(&sflags, local);
        __syncthreads();
        if (tid == 0) *mflag = sflags;
        // ---- weight conversion: fp32 -> f16 transposed+padded, once ----
        const float* Ws[4] = {Wg1, Wg2, Wv, Wt};
        #pragma unroll
        for (int mat = 0; mat < 4; ++mat) {
            const float* W = Ws[mat];
            _Float16* dst = w4 + mat * 64 * 72;
            for (int i = tid; i < 4096; i += 256) {
                int rr = i >> 6, c = i & 63;
                dst[c * 72 + rr] = (_Float16)W[i];
            }
        }
        return;
    }

    __shared__ __align__(16) _Float16 A_s[256 * 72];
    __shared__ __align__(16) _Float16 WT_s[64 * 72];

    const int r0 = blockIdx.x * 256;
    const float* x; const float* p; _Float16* o; int rb;
    if (r0 < MQ) { x = q; p = qpos; o = qp_h; rb = r0; }
    else         { x = k; p = kpos; o = kp_h; rb = r0 - MQ; }

    // Wqk transpose into LDS (float4 loads)
    #pragma unroll
    for (int j = 0; j < 4; ++j) {
        int i = (tid + j * 256) * 4;           // flat float index
        int rr = i >> 6, c4 = i & 63;
        floatx4 wv = *(const floatx4*)&Wqk[rr * 64 + c4];
        WT_s[(c4 + 0) * 72 + rr] = (_Float16)wv.x;
        WT_s[(c4 + 1) * 72 + rr] = (_Float16)wv.y;
        WT_s[(c4 + 2) * 72 + rr] = (_Float16)wv.z;
        WT_s[(c4 + 3) * 72 + rr] = (_Float16)wv.w;
    }
    // A staging: x+p, float4 loads, 8B f16 stores
    #pragma unroll
    for (int j = 0; j < 16; ++j) {
        int flat = tid + j * 256;              // float4 item id, 0..4095
        int rr = flat >> 4, c4 = (flat & 15) * 4;
        size_t g = (size_t)(rb + rr) * 64 + c4;
        floatx4 xv = *(const floatx4*)&x[g];
        floatx4 pv = *(const floatx4*)&p[g];
        half4v h;
        h[0] = (_Float16)(xv.x + pv.x); h[1] = (_Float16)(xv.y + pv.y);
        h[2] = (_Float16)(xv.z + pv.z); h[3] = (_Float16)(xv.w + pv.w);
        *(half4v*)&A_s[rr * 72 + c4] = h;
    }
    __syncthreads();

    const int w = tid >> 6, lane = tid & 63, m = lane & 15, qd = lane >> 4;
    const floatx4 fz = {0.f, 0.f, 0.f, 0.f};
    floatx4 acc[4][4];
    #pragma unroll
    for (int rt = 0; rt < 4; rt++)
        #pragma unroll
        for (int ct = 0; ct < 4; ct++) acc[rt][ct] = fz;

    #pragma unroll
    for (int kc = 0; kc < 2; ++kc) {
        const int k0 = kc * 32 + qd * 8;
        half8 b[4];
        #pragma unroll
        for (int ct = 0; ct < 4; ++ct)
            b[ct] = *(const half8*)&WT_s[(ct * 16 + m) * 72 + k0];
        #pragma unroll
        for (int rt = 0; rt < 4; ++rt) {
            half8 a = *(const half8*)&A_s[(w * 64 + rt * 16 + m) * 72 + k0];
            #pragma unroll
            for (int ct = 0; ct < 4; ++ct)
                acc[rt][ct] = __builtin_amdgcn_mfma_f32_16x16x32_f16(a, b[ct], acc[rt][ct], 0, 0, 0);
        }
    }
    // epilogue: acc -> A_s (f16, own wave's rows only), then vectorized global copy
    #pragma unroll
    for (int rt = 0; rt < 4; rt++) {
        #pragma unroll
        for (int ct = 0; ct < 4; ct++) {
            const int col = ct * 16 + m;
            const float bb = bqk[col];
            #pragma unroll
            for (int rg = 0; rg < 4; ++rg) {
                const int row = w * 64 + rt * 16 + qd * 4 + rg;
                A_s[row * 72 + col] = (_Float16)(acc[rt][ct][rg] + bb);
            }
        }
    }
    __syncthreads();
    #pragma unroll
    for (int j = 0; j < 8; ++j) {
        int ch = tid + j * 256;                // 16B chunk id, 0..2047
        int rr = ch >> 3, off = (ch & 7) * 8;
        *(half8*)&o[(size_t)(rb + rr) * 64 + off] = *(const half8*)&A_s[rr * 72 + off];
    }
}

// ---------------- Kernel B: fused edge-MLP + softmax + aggregate + out proj ----------------
__global__ __launch_bounds__(256, 2)
void cross_attn(const float* __restrict__ value, const unsigned char* __restrict__ maskraw,
                const int* __restrict__ mflag, const int* __restrict__ idx,
                const _Float16* __restrict__ qp_h, const _Float16* __restrict__ kp_h,
                const _Float16* __restrict__ w4,
                const float* __restrict__ bg1, const float* __restrict__ bg2,
                const float* __restrict__ bv,  const float* __restrict__ bt,
                float* __restrict__ out)
{
    __shared__ __align__(16) _Float16 W4_s[4 * 64 * 72];  // Wg1T, Wg2T, WvT, WtT
    __shared__ __align__(16) _Float16 D_s[256 * 72];
    __shared__ __align__(16) _Float16 res_s[16 * 72];
    __shared__ unsigned char mask_s[256];

    const int tid = threadIdx.x;
    const int q0 = blockIdx.x * 16;
    const int w = tid >> 6, lane = tid & 63, m = lane & 15, qd = lane >> 4;

    // ---- 1. value prefetch: issue ALL 16 float4 loads up front (no LDS deps) ----
    floatx4 vraw[16];
    {
        const size_t base = ((size_t)q0 * KNB + w * 64) * 64;
        #pragma unroll
        for (int rt = 0; rt < 4; ++rt)
            #pragma unroll
            for (int kc = 0; kc < 2; ++kc) {
                const float* vr = value + base + (size_t)(rt * 16 + m) * 64 + kc * 32 + qd * 8;
                vraw[(rt * 2 + kc) * 2 + 0] = *(const floatx4*)vr;
                vraw[(rt * 2 + kc) * 2 + 1] = *(const floatx4*)(vr + 4);
            }
    }

    // ---- 2. weight copy ws -> LDS (pre-converted f16, flat 16B chunks) ----
    #pragma unroll
    for (int j = 0; j < 9; ++j) {
        int ch = tid + j * 256;                // 0..2303
        *(half8*)&W4_s[ch * 8] = *(const half8*)&w4[ch * 8];
    }
    // ---- mask (per detected storage mode) ----
    {
        const int mode = *mflag;
        const size_t ei = (size_t)q0 * KNB + tid;
        unsigned char mv;
        if (mode & 2)      mv = maskraw[ei];
        else if (mode & 1) mv = ((const int*)maskraw)[ei] ? 1 : 0;
        else               mv = (((const float*)maskraw)[ei] != 0.f) ? 1 : 0;
        mask_s[tid] = mv;
    }
    // ---- d-gather: d = qp[mrow] - kp[idx], f16, 4B per lane per iter ----
    {
        const int pr = tid & 31;               // c = 2*pr
        #pragma unroll 8
        for (int i = 0; i < 32; ++i) {
            int e = (tid >> 5) + i * 8;        // edge id 0..255
            int nb = idx[(size_t)q0 * KNB + e];
            int mrow = q0 + (e >> 4);
            half2v qv = *(const half2v*)&qp_h[(size_t)mrow * 64 + pr * 2];
            half2v kv = *(const half2v*)&kp_h[(size_t)nb * 64 + pr * 2];
            half2v d; d[0] = qv[0] - kv[0]; d[1] = qv[1] - kv[1];
            *(half2v*)&D_s[e * 72 + pr * 2] = d;
        }
    }
    __syncthreads();

    const floatx4 fz = {0.f, 0.f, 0.f, 0.f};
    float bvv[4], bg1v[4], bg2v[4];
    #pragma unroll
    for (int ct = 0; ct < 4; ct++) {
        const int col = ct * 16 + m;
        bvv[ct] = bv[col]; bg1v[ct] = bg1[col]; bg2v[ct] = bg2[col];
    }

    const _Float16* Wg1T = W4_s;
    const _Float16* Wg2T = W4_s + 4608;
    const _Float16* WvT  = W4_s + 2 * 4608;
    const _Float16* WtT  = W4_s + 3 * 4608;

    // ---- h = relu(d @ Wg1 + bg1) ----
    floatx4 acce[4][4];
    #pragma unroll
    for (int rt = 0; rt < 4; rt++)
        #pragma unroll
        for (int ct = 0; ct < 4; ct++) acce[rt][ct] = fz;
    #pragma unroll
    for (int kc = 0; kc < 2; ++kc) {
        const int k0 = kc * 32 + qd * 8;
        half8 b[4];
        #pragma unroll
        for (int ct = 0; ct < 4; ++ct)
            b[ct] = *(const half8*)&Wg1T[(ct * 16 + m) * 72 + k0];
        #pragma unroll
        for (int rt = 0; rt < 4; ++rt) {
            half8 a = *(const half8*)&D_s[(w * 64 + rt * 16 + m) * 72 + k0];
            #pragma unroll
            for (int ct = 0; ct < 4; ++ct)
                acce[rt][ct] = __builtin_amdgcn_mfma_f32_16x16x32_f16(a, b[ct], acce[rt][ct], 0, 0, 0);
        }
    }
    __syncthreads();
    #pragma unroll
    for (int rt = 0; rt < 4; rt++)
        #pragma unroll
        for (int ct = 0; ct < 4; ct++) {
            const int col = ct * 16 + m;
            #pragma unroll
            for (int rg = 0; rg < 4; ++rg) {
                const int row = w * 64 + rt * 16 + qd * 4 + rg;
                float h = acce[rt][ct][rg] + bg1v[ct];
                D_s[row * 72 + col] = (_Float16)fmaxf(h, 0.f);
            }
        }
    __syncthreads();

    // ---- e = h @ Wg2 + bg2 ----
    #pragma unroll
    for (int rt = 0; rt < 4; rt++)
        #pragma unroll
        for (int ct = 0; ct < 4; ct++) acce[rt][ct] = fz;
    #pragma unroll
    for (int kc = 0; kc < 2; ++kc) {
        const int k0 = kc * 32 + qd * 8;
        half8 b[4];
        #pragma unroll
        for (int ct = 0; ct < 4; ++ct)
            b[ct] = *(const half8*)&Wg2T[(ct * 16 + m) * 72 + k0];
        #pragma unroll
        for (int rt = 0; rt < 4; ++rt) {
            half8 a = *(const half8*)&D_s[(w * 64 + rt * 16 + m) * 72 + k0];
            #pragma unroll
            for (int ct = 0; ct < 4; ++ct)
                acce[rt][ct] = __builtin_amdgcn_mfma_f32_16x16x32_f16(a, b[ct], acce[rt][ct], 0, 0, 0);
        }
    }

    // ---- convert prefetched value, then v = value @ Wv ----
    half8 vfrag[8];
    #pragma unroll
    for (int f = 0; f < 8; ++f) {
        floatx4 x0 = vraw[f * 2], x1 = vraw[f * 2 + 1];
        half8 a;
        #pragma unroll
        for (int j = 0; j < 4; ++j) { a[j] = (_Float16)x0[j]; a[4 + j] = (_Float16)x1[j]; }
        vfrag[f] = a;
    }
    floatx4 accv[4][4];
    #pragma unroll
    for (int rt = 0; rt < 4; rt++)
        #pragma unroll
        for (int ct = 0; ct < 4; ct++) accv[rt][ct] = fz;
    #pragma unroll
    for (int kc = 0; kc < 2; ++kc) {
        const int k0 = kc * 32 + qd * 8;
        half8 b[4];
        #pragma unroll
        for (int ct = 0; ct < 4; ++ct)
            b[ct] = *(const half8*)&WvT[(ct * 16 + m) * 72 + k0];
        #pragma unroll
        for (int rt = 0; rt < 4; ++rt) {
            half8 a = vfrag[rt * 2 + kc];
            #pragma unroll
            for (int ct = 0; ct < 4; ++ct)
                accv[rt][ct] = __builtin_amdgcn_mfma_f32_16x16x32_f16(a, b[ct], accv[rt][ct], 0, 0, 0);
        }
    }

    // ---- mask, softmax over neighbors, weighted aggregate ----
    #pragma unroll
    for (int rt = 0; rt < 4; rt++) {
        #pragma unroll
        for (int ct = 0; ct < 4; ct++) {
            float ev[4];
            #pragma unroll
            for (int rg = 0; rg < 4; ++rg) {
                const int erow = w * 64 + rt * 16 + qd * 4 + rg;
                float e = acce[rt][ct][rg] + bg2v[ct];
                ev[rg] = mask_s[erow] ? -1e12f : e;
            }
            float mx = fmaxf(fmaxf(ev[0], ev[1]), fmaxf(ev[2], ev[3]));
            mx = fmaxf(mx, __shfl_xor(mx, 16));
            mx = fmaxf(mx, __shfl_xor(mx, 32));
            float p[4], s = 0.f;
            #pragma unroll
            for (int rg = 0; rg < 4; ++rg) { p[rg] = __expf(ev[rg] - mx); s += p[rg]; }
            s += __shfl_xor(s, 16);
            s += __shfl_xor(s, 32);
            const float inv = 1.f / s;
            float t = 0.f;
            #pragma unroll
            for (int rg = 0; rg < 4; ++rg)
                t += p[rg] * inv * (accv[rt][ct][rg] + bvv[ct]);
            t += __shfl_xor(t, 16);
            t += __shfl_xor(t, 32);
            if (lane < 16) res_s[(w * 4 + rt) * 72 + ct * 16 + m] = (_Float16)t;
        }
    }
    __syncthreads();

    // ---- out = res @ Wt + bt (wave 0) ----
    if (w == 0) {
        floatx4 acco[4] = {fz, fz, fz, fz};
        #pragma unroll
        for (int kc = 0; kc < 2; ++kc) {
            const int k0 = kc * 32 + qd * 8;
            half8 a = *(const half8*)&res_s[m * 72 + k0];
            #pragma unroll
            for (int ct = 0; ct < 4; ++ct) {
                half8 b = *(const half8*)&WtT[(ct * 16 + m) * 72 + k0];
                acco[ct] = __builtin_amdgcn_mfma_f32_16x16x32_f16(a, b, acco[ct], 0, 0, 0);
            }
        }
        #pragma unroll
        for (int ct = 0; ct < 4; ++ct) {
            const int col = ct * 16 + m;
            const float bb = bt[col];
            #pragma unroll
            for (int rg = 0; rg < 4; ++rg) {
                const int row = qd * 4 + rg;
                out[(size_t)(q0 + row) * 64 + col] = acco[ct][rg] + bb;
            }
        }
    }
}

extern "C" void kernel_launch(void* const* d_in, const int* in_sizes, int n_in,
                              void* d_out, int out_size, void* d_ws, size_t ws_size,
                              hipStream_t stream) {
    const float* q     = (const float*)d_in[0];
    const float* k     = (const float*)d_in[1];
    const float* value = (const float*)d_in[2];
    const float* q_pos = (const float*)d_in[3];
    const float* k_pos = (const float*)d_in[4];
    const unsigned char* mask = (const unsigned char*)d_in[5];
    const int* knn     = (const int*)d_in[6];
    // d_in[7] = k_num scalar (16)
    const float* Wqk = (const float*)d_in[8];
    const float* bqk = (const float*)d_in[9];
    const float* Wv  = (const float*)d_in[10];
    const float* bv  = (const float*)d_in[11];
    const float* Wg1 = (const float*)d_in[12];
    const float* bg1 = (const float*)d_in[13];
    const float* Wg2 = (const float*)d_in[14];
    const float* bg2 = (const float*)d_in[15];
    const float* Wt  = (const float*)d_in[16];
    const float* bt  = (const float*)d_in[17];
    float* out = (float*)d_out;

    _Float16* qp_h = (_Float16*)d_ws;
    _Float16* kp_h = qp_h + (size_t)MQ * CCH;
    _Float16* w4   = kp_h + (size_t)NKEY * CCH;
    int* mflag     = (int*)(w4 + 4 * 64 * 72);
    const int* idx = knn + (size_t)MQ * KNB;   // row 1 of knearest_idx

    proj_prep<<<513, 256, 0, stream>>>(q, q_pos, k, k_pos, Wqk, bqk,
                                       Wg1, Wg2, Wv, Wt, mask,
                                       qp_h, kp_h, w4, mflag);
    cross_attn<<<MQ / 16, 256, 0, stream>>>(value, mask, mflag, idx, qp_h, kp_h, w4,
                                            bg1, bg2, bv, bt, out);
}